// Round 6
// baseline (212.854 us; speedup 1.0000x reference)
//
#include <hip/hip_runtime.h>
#include <hip/hip_bf16.h>

// QFD loss: out = 0.1 * sum_b diff_b^T A diff_b, A_ij = 1 - |i-j|/85.
// Per row: q = S^2 - (2/85)*(S*sumL - sumL2), S = sum d_i,
//   sumL = sum_{k<84} L_k, sumL2 = sum_{k<84} L_k^2  (L_k = prefix sums).
//
// R6 control-probe + candidate: R0-R5 all ~65 us with every pipe idle,
// invariant to occupancy/atomics/scan-depth/DMA-staging -> the shared
// stage->barrier->scan LDS structure itself is suspect. This kernel has
// NO LDS data path, NO barrier: each thread streams 4 whole rows
// (= exactly 85 aligned float4s) straight from global into the running
// scan, finalizing rows at compile-time-known unroll positions.

#define QFD_D 85
#define THREADS 128

__global__ __launch_bounds__(THREADS) void qfd_kernel(
    const float* __restrict__ in, const float* __restrict__ tgt,
    float* __restrict__ partial) {
    const int tid = blockIdx.x * THREADS + threadIdx.x;   // 0..65535
    // 4 rows = 340 floats = 85 float4s, base byte = tid*1360 (16B aligned)
    const float4* in4 = reinterpret_cast<const float4*>(in)  + tid * QFD_D;
    const float4* tg4 = reinterpret_cast<const float4*>(tgt) + tid * QFD_D;

    float l = 0.0f, a1 = 0.0f, b2 = 0.0f, qs = 0.0f;
    #pragma unroll
    for (int j = 0; j < 85; ++j) {
        float4 a = in4[j];
        float4 b = tg4[j];
        float e[4] = {a.x - b.x, a.y - b.y, a.z - b.z, a.w - b.w};
        #pragma unroll
        for (int c = 0; c < 4; ++c) {
            float v = fabsf(e[c]);
            l += v;
            a1 += l;
            b2 = fmaf(l, l, b2);
            if (((4 * j + c) % QFD_D) == QFD_D - 1) {   // compile-time
                float S = l;
                float sumL  = a1 - S;                   // drop L_84
                float sumL2 = fmaf(-S, S, b2);          // b2 - S^2
                qs += fmaf(S, S, -(2.0f / 85.0f) * (S * sumL - sumL2));
                l = 0.0f; a1 = 0.0f; b2 = 0.0f;
            }
        }
    }

    // Wave reduce, then 2-wave block combine, one plain store per block.
    #pragma unroll
    for (int m = 32; m > 0; m >>= 1)
        qs += __shfl_xor(qs, m, 64);
    __shared__ float ws[THREADS / 64];
    const int lane = threadIdx.x & 63;
    const int wave = threadIdx.x >> 6;
    if (lane == 0) ws[wave] = qs;
    __syncthreads();
    if (threadIdx.x == 0) partial[blockIdx.x] = ws[0] + ws[1];
}

// Stage 2: reduce n partials (n = 512), write 0.1 * sum. One block.
__global__ __launch_bounds__(256) void qfd_reduce_kernel(
    const float* __restrict__ partial, float* __restrict__ out, int n) {
    __shared__ float wsum[4];
    const int tid = threadIdx.x;
    float s = 0.0f;
    for (int i = tid; i < n; i += 256) s += partial[i];
    #pragma unroll
    for (int m = 32; m > 0; m >>= 1)
        s += __shfl_xor(s, m, 64);
    if ((tid & 63) == 0) wsum[tid >> 6] = s;
    __syncthreads();
    if (tid == 0) {
        float t = 0.0f;
        #pragma unroll
        for (int w = 0; w < 4; ++w) t += wsum[w];
        out[0] = 0.1f * t;
    }
}

extern "C" void kernel_launch(void* const* d_in, const int* in_sizes, int n_in,
                              void* d_out, int out_size, void* d_ws, size_t ws_size,
                              hipStream_t stream) {
    const float* in  = (const float*)d_in[0];
    const float* tgt = (const float*)d_in[1];
    float* out = (float*)d_out;
    float* partial = (float*)d_ws;              // 512 floats scratch

    const int B = in_sizes[0] / QFD_D;          // 262144 rows
    const int groups = B / 4;                   // 65536 threads, 4 rows each
    const int grid = groups / THREADS;          // 512 blocks

    qfd_kernel<<<grid, THREADS, 0, stream>>>(in, tgt, partial);
    qfd_reduce_kernel<<<1, 256, 0, stream>>>(partial, out, grid);
}